// Round 1
// baseline (1237.910 us; speedup 1.0000x reference)
//
#include <hip/hip_runtime.h>
#include <math.h>

#define T_STEPS 256
#define BATCH   256
#define DDIM    128
#define NH      10

typedef int v2i __attribute__((ext_vector_type(2)));

// ---------- DPP helpers (VALU pipe) ----------
template<int CTRL, int RMASK, int BMASK>
__device__ __forceinline__ float dppz(float x){
  return __int_as_float(__builtin_amdgcn_update_dpp(
      0, __float_as_int(x), CTRL, RMASK, BMASK, true));
}
template<int CTRL>
__device__ __forceinline__ float qperm(float x){
  int xi = __float_as_int(x);
  return __int_as_float(__builtin_amdgcn_update_dpp(xi, xi, CTRL, 0xF, 0xF, false));
}
// xor-4 / xor-8 within a 16-lane row (proven R6/R7).
__device__ __forceinline__ float lane_xor4(float x){
  int xi = __float_as_int(x);
  int t = __builtin_amdgcn_update_dpp(xi, xi, 0x104, 0xF, 0x5, false); // row_shl:4, banks {0,2}
  t     = __builtin_amdgcn_update_dpp(t,  xi, 0x114, 0xF, 0xA, false); // row_shr:4, banks {1,3}
  return __int_as_float(t);
}
__device__ __forceinline__ float lane_xor8(float x){
  int xi = __float_as_int(x);
  int t = __builtin_amdgcn_update_dpp(xi, xi, 0x108, 0xF, 0x3, false); // row_shl:8, banks {0,1}
  t     = __builtin_amdgcn_update_dpp(t,  xi, 0x118, 0xF, 0xC, false); // row_shr:8, banks {2,3}
  return __int_as_float(t);
}
// Canonical wave64 ladder (proven R4+): lane 63 ends with the full sum.
__device__ __forceinline__ float red63(float v){
  v += dppz<0x111, 0xF, 0xF>(v);
  v += dppz<0x112, 0xF, 0xF>(v);
  v += dppz<0x114, 0xF, 0xE>(v);
  v += dppz<0x118, 0xF, 0xC>(v);
  v += dppz<0x142, 0xA, 0xF>(v);
  v += dppz<0x143, 0xC, 0xF>(v);
  return v;
}
__device__ __forceinline__ float wave_sum_b(float v){
  return __int_as_float(__builtin_amdgcn_readlane(__float_as_int(red63(v)), 63));
}
__device__ __forceinline__ float qp2(float x){ return qperm<0x4E>(x); }
__device__ __forceinline__ float qp1(float x){ return qperm<0xB1>(x); }

// Partner fetch across lane bit5 / bit4 via gfx950 permlane swaps (VALU pipe,
// no lgkm wait). With both operands = x, the result pair {r.x, r.y} holds
// {own, partner} in SOME order at every lane regardless of the ISA's swap
// direction, so partner = r.x ^ r.y ^ own — bit-exact and direction-agnostic.
#if __has_builtin(__builtin_amdgcn_permlane32_swap)
__device__ __forceinline__ float pl32_partner(float x){
  int xi = __float_as_int(x);
  v2i r = __builtin_amdgcn_permlane32_swap(xi, xi, false, false);
  return __int_as_float(r.x ^ r.y ^ xi);
}
#else
__device__ __forceinline__ float pl32_partner(float x){ return __shfl_xor(x, 32, 64); }
#endif
#if __has_builtin(__builtin_amdgcn_permlane16_swap)
__device__ __forceinline__ float pl16_partner(float x){
  int xi = __float_as_int(x);
  v2i r = __builtin_amdgcn_permlane16_swap(xi, xi, false, false);
  return __int_as_float(r.x ^ r.y ^ xi);
}
#else
__device__ __forceinline__ float pl16_partner(float x){
  // ds_swizzle xor-16 (BitMode 0x401F) — documented-correct fallback
  return __int_as_float(__builtin_amdgcn_ds_swizzle(__float_as_int(x), 0x401F));
}
#endif

#define NREG 8   // 8 complex amps per lane per wave (half statevector)

// RX on a reg-bit wire (bit BIT of the 3 reg bits). Pure VALU.
template<int BIT>
__device__ __forceinline__ void rx_reg(float c, float s, float* re, float* im){
  #pragma unroll
  for (int r = 0; r < NREG; ++r){
    if (r & (1 << BIT)) continue;
    const int r1 = r | (1 << BIT);
    float a0 = re[r], b0 = im[r], a1 = re[r1], b1 = im[r1];
    re[r]  = fmaf(c, a0,  s * b1);
    im[r]  = fmaf(c, b0, -s * a1);
    re[r1] = fmaf(c, a1,  s * b0);
    im[r1] = fmaf(c, b1, -s * a0);
  }
}
// RX on a lane-bit wire with an in-register partner fetch (DPP or permlane).
#define RX_LANE_F(FETCH, cv, sv)                                               \
  { _Pragma("unroll")                                                          \
    for (int r = 0; r < NREG; ++r){                                            \
      float oa = FETCH(re[r]);                                                 \
      float ob = FETCH(im[r]);                                                 \
      re[r] = fmaf(cv, re[r],  sv * ob);                                       \
      im[r] = fmaf(cv, im[r], -sv * oa);                                       \
    } }

// ================= R8 layout (unchanged algebra) =================
// Wave pair per gate: 512 amps/wave = 64 lanes x 8 regs. Wires 0..5 -> lane
// bits 5..0, wire 6 -> wave bit (LDS exchange), wires 7,8,9 -> reg bits 2,1,0.
// Measurement parity sets / signs: verified R1-R7 (see prior session).
__global__ void __launch_bounds__(512)
__attribute__((amdgpu_waves_per_eu(2)))
qlstm_kernel(const float* __restrict__ inp, const float* __restrict__ rxp,
             const float* __restrict__ Wf, const float* __restrict__ bf,
             const float* __restrict__ Wi, const float* __restrict__ bi,
             const float* __restrict__ Wg, const float* __restrict__ bg,
             const float* __restrict__ Wo, const float* __restrict__ bo,
             float* __restrict__ out)
{
  const int b    = blockIdx.x;
  const int tid  = threadIdx.x;
  const int wv   = tid >> 6;        // 0..7
  const int g    = wv >> 1;         // gate 0..3 (f,i,g,o)
  const int half = wv & 1;          // statevector half (wire-6 / wave bit)
  const int lane = tid & 63;

  // wire-6 exchange buffer: [gate][half][chunk][lane]
  __shared__ float4 Sx[4][2][4][64];
  // measurement partials, transposed for float4 combine reads:
  // partv[half][j].{x,y,z,w} = gate {f,i,g,o} partial for hidden unit j.
  // Slots j=10..63 stay 0 forever.
  __shared__ float4 partv[2][64];
  ((float*)partv)[tid] = 0.f;       // 2*64*4 = 512 = blockDim

  const float* Wp = (g == 0) ? Wf : (g == 1) ? Wi : (g == 2) ? Wg : Wo;
  const float* bp = (g == 0) ? bf : (g == 1) ? bi : (g == 2) ? bg : bo;

  float wA[NH], wB[NH], wC[NH], bT[NH];
  #pragma unroll
  for (int w = 0; w < NH; ++w){
    wA[w] = Wp[w*138 + lane];
    wB[w] = Wp[w*138 + 64 + lane];
    wC[w] = (lane < NH) ? Wp[w*138 + 128 + lane] : 0.f;
    bT[w] = bp[w] + rxp[w];
  }
  float pc[NH], ps[NH];
  #pragma unroll
  for (int w = 0; w < NH; ++w){
    float th = 0.5f * rxp[w];
    pc[w] = cosf(th);
    ps[w] = sinf(th);
  }

  // ---- hoisted lane/wave constants ----
  const int l5 = (lane>>5)&1, l4 = (lane>>4)&1, l3 = (lane>>3)&1;
  const int l2 = (lane>>2)&1, l1 = (lane>>1)&1, l0 = lane&1;
  const int pb2 = l4^l3, pb3 = l3^l2, pb4 = l2^l1, pb5 = l1^l0;
  const int a0 = l5, a1 = l5^l4;
  const int a6w = l0 ^ half;                       // beta6
  const int n_base = pb2 + pb3 + pb4 + pb5 + a6w;

  // phase constants (-i)^k per reg (step-invariant)
  float cre8[NREG], cim8[NREG];
  #pragma unroll
  for (int r = 0; r < NREG; ++r){
    const int R0 = r&1, R1 = (r>>1)&1, R2 = (r>>2)&1;
    int k = (n_base + (a0^R0) + (a1^R0) + (half^R2) + (R2^R1) + (R1^R0)) & 3;
    cre8[r] = (k==0) ? 1.f : (k==2) ? -1.f : 0.f;
    cim8[r] = (k==1) ? -1.f : (k==3) ? 1.f : 0.f;
  }

  // measurement lane signs
  const float ls0 = (__popc(lane & 0x1F) & 1) ? -1.f : 1.f;
  const float ls1 = (__popc(lane & 0x30) & 1) ? -1.f : 1.f;
  const float ls2 = (__popc(lane & 0x38) & 1) ? -1.f : 1.f;
  const float ls3 = (__popc(lane & 0x3C) & 1) ? -1.f : 1.f;
  const float ls4 = (__popc(lane & 0x3E) & 1) ? -1.f : 1.f;
  const float ls5 = (__popc(lane & 0x3F) & 1) ? -1.f : 1.f;
  // wave-sign at combine: sigma = -1 for hidden units {0, 6..9}
  const float sig = (lane == 0 || lane >= 6) ? -1.f : 1.f;

  float h = 0.f, c = 0.f;   // lane j holds h_j, c_j redundantly in every wave

  const float* x0 = inp + (size_t)b * DDIM;
  float xa = x0[lane];
  float xb = x0[64 + lane];

  // x-part of pre-activation for step 0 (bias + RX param folded in).
  // px[] is software-pipelined: recomputed mid-step for step t+1.
  float px[NH];
  #pragma unroll
  for (int w = 0; w < NH; ++w)
    px[w] = bT[w] + wave_sum_b(fmaf(xa, wA[w], xb * wB[w]));

  __syncthreads();

  #pragma unroll 1
  for (int t = 0; t < T_STEPS; ++t){
    if (t + 1 < T_STEPS){
      const float* nx = inp + ((size_t)(t+1) * BATCH + b) * DDIM;
      xa = nx[lane];
      xb = nx[64 + lane];
    }

    // ---- gate pre-activation half-angles ----
    // th = 0.5*(px[w] + hdot), hdot = sum_{j<10} h_j*wC[w][j]:
    // wC is zero outside lanes 0..9, so a 4-stage 16-lane butterfly suffices
    // (rows 1..3 reduce zeros); full sum lands on every lane of row 0.
    float cs[NH], sn[NH];
    #pragma unroll
    for (int w = 0; w < NH; ++w){
      float v = h * wC[w];
      v += qp1(v);
      v += qp2(v);
      v += lane_xor4(v);
      v += lane_xor8(v);
      float hd = __int_as_float(__builtin_amdgcn_readlane(__float_as_int(v), 0));
      float th = 0.5f * (px[w] + hd);
      cs[w] = __cosf(th);
      sn[w] = __sinf(th);
    }

    // ---- build half-statevector: u[j] = prod-state(x+p) at K j ----
    float f2 = pb2 ? sn[2] : cs[2];
    float f3 = pb3 ? sn[3] : cs[3];
    float f4 = pb4 ? sn[4] : cs[4];
    float f5 = pb5 ? sn[5] : cs[5];
    float m2345 = ((f2*f3)*(f4*f5)) * (a6w ? sn[6] : cs[6]);  // wire-6 factor folded

    float q0 = (a0 ? sn[0] : cs[0]) * (a1 ? sn[1] : cs[1]);
    float q1 = (a0 ? cs[0] : sn[0]) * (a1 ? cs[1] : sn[1]);
    float Z0 = m2345 * q0, Z1 = m2345 * q1;

    float u7  = half ? sn[7] : cs[7];
    float u7b = half ? cs[7] : sn[7];
    float t78[4];
    t78[0] = u7  * cs[8];   // R2=0,R1=0
    t78[1] = u7  * sn[8];   // R2=0,R1=1
    t78[2] = u7b * sn[8];   // R2=1,R1=0
    t78[3] = u7b * cs[8];   // R2=1,R1=1

    float re[NREG], im[NREG];
    #pragma unroll
    for (int r = 0; r < NREG; ++r){
      const int b9 = ((r >> 1) ^ r) & 1;          // R1^R0
      float A = t78[r >> 1] * (b9 ? sn[9] : cs[9]);
      float m = A * ((r & 1) ? Z1 : Z0);
      re[r] = m * cre8[r];
      im[r] = m * cim8[r];
    }

    // ---- RX(p): lane wires 0..5 (all in-register now), reg wires 7..9 ----
    RX_LANE_F(pl32_partner, pc[0], ps[0])
    RX_LANE_F(pl16_partner, pc[1], ps[1])
    RX_LANE_F(lane_xor8,    pc[2], ps[2])
    RX_LANE_F(lane_xor4,    pc[3], ps[3])
    RX_LANE_F(qp2,          pc[4], ps[4])
    RX_LANE_F(qp1,          pc[5], ps[5])
    rx_reg<2>(pc[7], ps[7], re, im);
    rx_reg<1>(pc[8], ps[8], re, im);
    rx_reg<0>(pc[9], ps[9], re, im);

    // wire 6 (wave bit): exchange full half-state with partner wave via LDS
    Sx[g][half][0][lane] = make_float4(re[0], re[1], re[2], re[3]);
    Sx[g][half][1][lane] = make_float4(re[4], re[5], re[6], re[7]);
    Sx[g][half][2][lane] = make_float4(im[0], im[1], im[2], im[3]);
    Sx[g][half][3][lane] = make_float4(im[4], im[5], im[6], im[7]);

    // ---- pipelined x-part of NEXT step's pre-activation ----
    // Pure VALU/DPP; sits in the ds_write-drain + barrier shadow, off the
    // h -> th critical path of step t+1.
    if (t + 1 < T_STEPS){
      #pragma unroll
      for (int w = 0; w < NH; ++w)
        px[w] = bT[w] + wave_sum_b(fmaf(xa, wA[w], xb * wB[w]));
    }

    __syncthreads();
    {
      float4 pr0 = Sx[g][half^1][0][lane];
      float4 pr1 = Sx[g][half^1][1][lane];
      float4 pi0 = Sx[g][half^1][2][lane];
      float4 pi1 = Sx[g][half^1][3][lane];
      float pre[NREG] = {pr0.x,pr0.y,pr0.z,pr0.w, pr1.x,pr1.y,pr1.z,pr1.w};
      float pim[NREG] = {pi0.x,pi0.y,pi0.z,pi0.w, pi1.x,pi1.y,pi1.z,pi1.w};
      const float c6 = pc[6], s6 = ps[6];
      #pragma unroll
      for (int r = 0; r < NREG; ++r){
        re[r] = fmaf(c6, re[r],  s6 * pim[r]);
        im[r] = fmaf(c6, im[r], -s6 * pre[r]);
      }
    }

    // ---- PauliZ partials (this wave's 512 amps); totals land in lane 63 ----
    float tot = 0.f, q4 = 0.f, q6 = 0.f, q7 = 0.f;
    #pragma unroll
    for (int r = 0; r < NREG; ++r){
      float p = fmaf(re[r], re[r], im[r]*im[r]);
      tot += p;
      q4 += ((__popc(r & 0x4) & 1) ? -p : p);
      q6 += ((__popc(r & 0x6) & 1) ? -p : p);
      q7 += ((__popc(r & 0x7) & 1) ? -p : p);
    }
    float P0 = red63(ls0 * q7);
    float P1 = red63(ls1 * tot);
    float P2 = red63(ls2 * tot);
    float P3 = red63(ls3 * tot);
    float P4 = red63(ls4 * tot);
    float P5 = red63(ls5 * tot);   // serves S5 (sigma +) and S6 (sigma -)
    float P7 = red63(ls5 * q4);
    float P8 = red63(ls5 * q6);
    float P9 = red63(ls5 * q7);
    if (lane == 63){
      float vals[10] = {P0,P1,P2,P3,P4,P5,P5,P7,P8,P9};
      #pragma unroll
      for (int j = 0; j < 10; ++j)
        ((float*)&partv[half][j])[g] = vals[j];
    }
    __syncthreads();

    // ---- combine partials + activations + cell (every lane, every wave) ----
    float4 eL = partv[0][lane];
    float4 eH = partv[1][lane];
    float E0 = fmaf(sig, eH.x, eL.x);
    float E1 = fmaf(sig, eH.y, eL.y);
    float E2 = fmaf(sig, eH.z, eL.z);
    float E3 = fmaf(sig, eH.w, eL.w);
    float fv = 1.f / (1.f + __expf(-E0));
    float iv = 1.f / (1.f + __expf(-E1));
    float e2g = __expf(2.f * E2);
    float gv = (e2g - 1.f) / (e2g + 1.f);
    float ov = 1.f / (1.f + __expf(-E3));
    c = fmaf(fv, c, iv * gv);
    float e2c = __expf(2.f * c);
    h = ov * ((e2c - 1.f) / (e2c + 1.f));

    if (wv == 0 && lane < NH)
      out[((size_t)t * BATCH + b) * NH + lane] = h;
  }

  // hT, cT
  if (wv == 0 && lane < NH){
    const size_t ysN = (size_t)T_STEPS * BATCH * NH;
    out[ysN + (size_t)b * NH + lane]                      = h;
    out[ysN + (size_t)BATCH * NH + (size_t)b * NH + lane] = c;
  }
}

extern "C" void kernel_launch(void* const* d_in, const int* in_sizes, int n_in,
                              void* d_out, int out_size, void* d_ws, size_t ws_size,
                              hipStream_t stream)
{
  qlstm_kernel<<<BATCH, 512, 0, stream>>>(
      (const float*)d_in[0], (const float*)d_in[1],
      (const float*)d_in[2], (const float*)d_in[3],
      (const float*)d_in[4], (const float*)d_in[5],
      (const float*)d_in[6], (const float*)d_in[7],
      (const float*)d_in[8], (const float*)d_in[9],
      (float*)d_out);
}

// Round 2
// 982.473 us; speedup vs baseline: 1.2600x; 1.2600x over previous
//
#include <hip/hip_runtime.h>
#include <math.h>

#define T_STEPS 256
#define BATCH   256
#define DDIM    128
#define NH      10

typedef float v2f __attribute__((ext_vector_type(2)));

__device__ __forceinline__ v2f sp(float x){ v2f r; r.x = x; r.y = x; return r; }
#define PKFMA(a,b,c) __builtin_elementwise_fma((a),(b),(c))

// ---------- DPP helpers (VALU pipe) ----------
template<int CTRL, int RMASK, int BMASK>
__device__ __forceinline__ float dppz(float x){
  return __int_as_float(__builtin_amdgcn_update_dpp(
      0, __float_as_int(x), CTRL, RMASK, BMASK, true));
}
template<int CTRL>
__device__ __forceinline__ float qperm(float x){
  int xi = __float_as_int(x);
  return __int_as_float(__builtin_amdgcn_update_dpp(xi, xi, CTRL, 0xF, 0xF, false));
}
// Canonical wave64 ladder (proven R4+): lane 63 ends with the full sum.
__device__ __forceinline__ float red63(float v){
  v += dppz<0x111, 0xF, 0xF>(v);
  v += dppz<0x112, 0xF, 0xF>(v);
  v += dppz<0x114, 0xF, 0xE>(v);
  v += dppz<0x118, 0xF, 0xC>(v);
  v += dppz<0x142, 0xA, 0xF>(v);
  v += dppz<0x143, 0xC, 0xF>(v);
  return v;
}
__device__ __forceinline__ float wave_sum_b(float v){
  return __int_as_float(__builtin_amdgcn_readlane(__float_as_int(red63(v)), 63));
}
__device__ __forceinline__ float qp2(float x){ return qperm<0x4E>(x); }  // quad xor2
__device__ __forceinline__ float qp1(float x){ return qperm<0xB1>(x); }  // quad xor1

// ---------- ds-pipe xor fetchers (offload from the saturated VALU) ----------
// ds_swizzle BitMode: offset = (xor<<10)|(or<<5)|and, and=0x1F keeps lane bits.
__device__ __forceinline__ float dsx32(float x){ return __shfl_xor(x, 32, 64); }
__device__ __forceinline__ float dsx16(float x){
  return __int_as_float(__builtin_amdgcn_ds_swizzle(__float_as_int(x), 0x401F));
}
__device__ __forceinline__ float dsx8(float x){
  return __int_as_float(__builtin_amdgcn_ds_swizzle(__float_as_int(x), 0x201F));
}
__device__ __forceinline__ float dsx4(float x){
  return __int_as_float(__builtin_amdgcn_ds_swizzle(__float_as_int(x), 0x101F));
}

#define NK 4   // 4 packed pairs = 8 complex amps per lane (half statevector)

// RX on a lane-bit wire, packed: 2 fetches + 2 pk ops per pair.
#define RX_LANE_PK(FETCH, cv, sv)                                              \
  { const v2f cc_ = sp(cv), ss_ = sp(sv);                                      \
    _Pragma("unroll")                                                          \
    for (int k = 0; k < NK; ++k){                                              \
      v2f oa, ob;                                                              \
      oa.x = FETCH(RE[k].x); oa.y = FETCH(RE[k].y);                            \
      ob.x = FETCH(IM[k].x); ob.y = FETCH(IM[k].y);                            \
      RE[k] = PKFMA(cc_, RE[k], ss_ * ob);                                     \
      IM[k] = PKFMA(cc_, IM[k], -(ss_ * oa));                                  \
    } }

// RX on reg bit R2 (XB=2) / R1 (XB=1): partner pair is k^XB, no component swap.
template<int XB>
__device__ __forceinline__ void rx_reg_pk(float c, float s, v2f* RE, v2f* IM){
  const v2f cc = sp(c), ss = sp(s);
  v2f oR[NK], oI[NK];
  #pragma unroll
  for (int k = 0; k < NK; ++k){ oR[k] = RE[k]; oI[k] = IM[k]; }
  #pragma unroll
  for (int k = 0; k < NK; ++k){
    RE[k] = PKFMA(cc, oR[k],  ss * oI[k ^ XB]);
    IM[k] = PKFMA(cc, oI[k], -(ss * oR[k ^ XB]));
  }
}
// RX on reg bit R0: partner is the swapped component of the same pair.
__device__ __forceinline__ void rx_reg9_pk(float c, float s, v2f* RE, v2f* IM){
  const v2f cc = sp(c), ss = sp(s);
  #pragma unroll
  for (int k = 0; k < NK; ++k){
    v2f oa = __builtin_shufflevector(RE[k], RE[k], 1, 0);
    v2f ob = __builtin_shufflevector(IM[k], IM[k], 1, 0);
    RE[k] = PKFMA(cc, RE[k],  ss * ob);
    IM[k] = PKFMA(cc, IM[k], -(ss * oa));
  }
}

// ================= R8 layout (verified algebra, unchanged) =================
// Wave pair per gate: 512 amps/wave = 64 lanes x 8 regs (4 v2f pairs).
// Wires 0..5 -> lane bits 5..0, wire 6 -> wave bit (LDS exchange),
// wires 7,8,9 -> reg bits 2,1,0 (R0 = packed component).
__global__ void __launch_bounds__(512)
__attribute__((amdgpu_waves_per_eu(2)))
qlstm_kernel(const float* __restrict__ inp, const float* __restrict__ rxp,
             const float* __restrict__ Wf, const float* __restrict__ bf,
             const float* __restrict__ Wi, const float* __restrict__ bi,
             const float* __restrict__ Wg, const float* __restrict__ bg,
             const float* __restrict__ Wo, const float* __restrict__ bo,
             float* __restrict__ out)
{
  const int b    = blockIdx.x;
  const int tid  = threadIdx.x;
  const int wv   = tid >> 6;        // 0..7
  const int g    = wv >> 1;         // gate 0..3 (f,i,g,o)
  const int half = wv & 1;          // statevector half (wire-6 / wave bit)
  const int lane = tid & 63;

  // wire-6 exchange buffer: [gate][half][chunk][lane]
  __shared__ float4 Sx[4][2][4][64];
  // measurement partials, transposed: partv[half][j].{x,y,z,w} = gate f,i,g,o
  __shared__ float4 partv[2][64];
  ((float*)partv)[tid] = 0.f;       // 2*64*4 = 512 = blockDim

  const float* Wp = (g == 0) ? Wf : (g == 1) ? Wi : (g == 2) ? Wg : Wo;
  const float* bp = (g == 0) ? bf : (g == 1) ? bi : (g == 2) ? bg : bo;

  // Pre-scale weights by 0.5 (half-angle) * 1/(2pi) (v_sin/v_cos take
  // revolutions) so the per-step angle needs zero extra multiplies.
  const float WSC = 0.07957747154594767f;   // 1/(4*pi)
  v2f WA[5], WB[5], WC[5];
  float bT[NH];
  #pragma unroll
  for (int j = 0; j < 5; ++j){
    const int w0 = 2*j, w1 = 2*j + 1;
    WA[j].x = WSC * Wp[w0*138 + lane];        WA[j].y = WSC * Wp[w1*138 + lane];
    WB[j].x = WSC * Wp[w0*138 + 64 + lane];   WB[j].y = WSC * Wp[w1*138 + 64 + lane];
    WC[j].x = (lane < NH) ? WSC * Wp[w0*138 + 128 + lane] : 0.f;
    WC[j].y = (lane < NH) ? WSC * Wp[w1*138 + 128 + lane] : 0.f;
  }
  #pragma unroll
  for (int w = 0; w < NH; ++w) bT[w] = WSC * (bp[w] + rxp[w]);

  float pc[NH], ps[NH];
  #pragma unroll
  for (int w = 0; w < NH; ++w){
    float th = 0.5f * rxp[w];
    pc[w] = cosf(th);
    ps[w] = sinf(th);
  }

  // ---- hoisted lane/wave constants ----
  const int l5 = (lane>>5)&1, l4 = (lane>>4)&1, l3 = (lane>>3)&1;
  const int l2 = (lane>>2)&1, l1 = (lane>>1)&1, l0 = lane&1;
  const int pb2 = l4^l3, pb3 = l3^l2, pb4 = l2^l1, pb5 = l1^l0;
  const int a0 = l5, a1 = l5^l4;
  const int a6w = l0 ^ half;                       // beta6
  const int n_base = pb2 + pb3 + pb4 + pb5 + a6w;

  // phase constants (-i)^k per reg (step-invariant), packed over R0
  v2f CRE[NK], CIM[NK];
  #pragma unroll
  for (int r = 0; r < 2*NK; ++r){
    const int R0 = r&1, R1 = (r>>1)&1, R2 = (r>>2)&1;
    int k = (n_base + (a0^R0) + (a1^R0) + (half^R2) + (R2^R1) + (R1^R0)) & 3;
    float cr = (k==0) ? 1.f : (k==2) ? -1.f : 0.f;
    float ci = (k==1) ? -1.f : (k==3) ? 1.f : 0.f;
    if (R0){ CRE[r>>1].y = cr; CIM[r>>1].y = ci; }
    else   { CRE[r>>1].x = cr; CIM[r>>1].x = ci; }
  }

  // measurement lane signs
  const float ls0 = (__popc(lane & 0x1F) & 1) ? -1.f : 1.f;
  const float ls1 = (__popc(lane & 0x30) & 1) ? -1.f : 1.f;
  const float ls2 = (__popc(lane & 0x38) & 1) ? -1.f : 1.f;
  const float ls3 = (__popc(lane & 0x3C) & 1) ? -1.f : 1.f;
  const float ls4 = (__popc(lane & 0x3E) & 1) ? -1.f : 1.f;
  const float ls5 = (__popc(lane & 0x3F) & 1) ? -1.f : 1.f;
  // wave-sign at combine: sigma = -1 for hidden units {0, 6..9}
  const float sig = (lane == 0 || lane >= 6) ? -1.f : 1.f;

  float h = 0.f, c = 0.f;   // lane j holds h_j, c_j redundantly in every wave

  const float* x0 = inp + (size_t)b * DDIM;
  float xa = x0[lane];
  float xb = x0[64 + lane];

  __syncthreads();

  #pragma unroll 1
  for (int t = 0; t < T_STEPS; ++t){
    float xaC = xa, xbC = xb;
    if (t + 1 < T_STEPS){
      const float* nx = inp + ((size_t)(t+1) * BATCH + b) * DDIM;
      xa = nx[lane];
      xb = nx[64 + lane];
    }

    // ---- gate pre-activation angles (in revolutions; scale folded into W) ----
    float cs[NH], sn[NH];
    {
      const v2f xav = sp(xaC), xbv = sp(xbC), hv = sp(h);
      #pragma unroll
      for (int j = 0; j < 5; ++j){
        v2f pv = PKFMA(xav, WA[j], PKFMA(xbv, WB[j], hv * WC[j]));
        float t0 = bT[2*j]   + wave_sum_b(pv.x);
        float t1 = bT[2*j+1] + wave_sum_b(pv.y);
        cs[2*j]   = __builtin_amdgcn_cosf(t0);
        sn[2*j]   = __builtin_amdgcn_sinf(t0);
        cs[2*j+1] = __builtin_amdgcn_cosf(t1);
        sn[2*j+1] = __builtin_amdgcn_sinf(t1);
      }
    }

    // ---- build half-statevector: u[j] = prod-state(x+p) at K j ----
    float f2 = pb2 ? sn[2] : cs[2];
    float f3 = pb3 ? sn[3] : cs[3];
    float f4 = pb4 ? sn[4] : cs[4];
    float f5 = pb5 ? sn[5] : cs[5];
    float m2345 = ((f2*f3)*(f4*f5)) * (a6w ? sn[6] : cs[6]);  // wire-6 folded

    float q0 = (a0 ? sn[0] : cs[0]) * (a1 ? sn[1] : cs[1]);
    float q1 = (a0 ? cs[0] : sn[0]) * (a1 ? cs[1] : sn[1]);
    v2f ZZ; ZZ.x = m2345 * q0; ZZ.y = m2345 * q1;

    float u7  = half ? sn[7] : cs[7];
    float u7b = half ? cs[7] : sn[7];
    float t78[4];
    t78[0] = u7  * cs[8];   // k=0: R2=0,R1=0
    t78[1] = u7  * sn[8];   // k=1: R2=0,R1=1
    t78[2] = u7b * sn[8];   // k=2: R2=1,R1=0
    t78[3] = u7b * cs[8];   // k=3: R2=1,R1=1

    v2f s9a; s9a.x = cs[9]; s9a.y = sn[9];   // k even: b9 = R1^R0 = (0,1)
    v2f s9b; s9b.x = sn[9]; s9b.y = cs[9];   // k odd:  b9 = (1,0)

    v2f RE[NK], IM[NK];
    #pragma unroll
    for (int k = 0; k < NK; ++k){
      v2f M = (sp(t78[k]) * ((k & 1) ? s9b : s9a)) * ZZ;
      RE[k] = M * CRE[k];
      IM[k] = M * CIM[k];
    }

    // ---- RX(p): lane wires 0..5 (ds-pipe fetch for 0..3), reg wires 7..9 ----
    RX_LANE_PK(dsx32, pc[0], ps[0])
    RX_LANE_PK(dsx16, pc[1], ps[1])
    RX_LANE_PK(dsx8,  pc[2], ps[2])
    RX_LANE_PK(dsx4,  pc[3], ps[3])
    RX_LANE_PK(qp2,   pc[4], ps[4])
    RX_LANE_PK(qp1,   pc[5], ps[5])
    rx_reg_pk<2>(pc[7], ps[7], RE, IM);
    rx_reg_pk<1>(pc[8], ps[8], RE, IM);
    rx_reg9_pk  (pc[9], ps[9], RE, IM);

    // wire 6 (wave bit): exchange full half-state with partner wave via LDS
    Sx[g][half][0][lane] = make_float4(RE[0].x, RE[0].y, RE[1].x, RE[1].y);
    Sx[g][half][1][lane] = make_float4(RE[2].x, RE[2].y, RE[3].x, RE[3].y);
    Sx[g][half][2][lane] = make_float4(IM[0].x, IM[0].y, IM[1].x, IM[1].y);
    Sx[g][half][3][lane] = make_float4(IM[2].x, IM[2].y, IM[3].x, IM[3].y);
    __syncthreads();
    {
      float4 pr0 = Sx[g][half^1][0][lane];
      float4 pr1 = Sx[g][half^1][1][lane];
      float4 pi0 = Sx[g][half^1][2][lane];
      float4 pi1 = Sx[g][half^1][3][lane];
      v2f PR[NK], PI[NK];
      PR[0].x = pr0.x; PR[0].y = pr0.y; PR[1].x = pr0.z; PR[1].y = pr0.w;
      PR[2].x = pr1.x; PR[2].y = pr1.y; PR[3].x = pr1.z; PR[3].y = pr1.w;
      PI[0].x = pi0.x; PI[0].y = pi0.y; PI[1].x = pi0.z; PI[1].y = pi0.w;
      PI[2].x = pi1.x; PI[2].y = pi1.y; PI[3].x = pi1.z; PI[3].y = pi1.w;
      const v2f c6 = sp(pc[6]), s6 = sp(ps[6]);
      #pragma unroll
      for (int k = 0; k < NK; ++k){
        RE[k] = PKFMA(c6, RE[k],  s6 * PI[k]);
        IM[k] = PKFMA(c6, IM[k], -(s6 * PR[k]));
      }
    }

    // ---- PauliZ partials: packed |psi|^2 + shared pair-tree ----
    v2f Pk[NK];
    #pragma unroll
    for (int k = 0; k < NK; ++k) Pk[k] = PKFMA(RE[k], RE[k], IM[k] * IM[k]);
    float A0 = Pk[0].x + Pk[0].y, A1 = Pk[1].x + Pk[1].y;
    float A2 = Pk[2].x + Pk[2].y, A3 = Pk[3].x + Pk[3].y;
    float B0 = Pk[0].x - Pk[0].y, B1 = Pk[1].x - Pk[1].y;
    float B2 = Pk[2].x - Pk[2].y, B3 = Pk[3].x - Pk[3].y;
    float su = A0 + A1, sv = A2 + A3;
    float tot = su + sv;                 // plain sum
    float q4  = su - sv;                 // sign on R2
    float q6  = (A0 - A1) - (A2 - A3);   // sign parity of R2^R1 mask 0x6
    float q7  = (B0 - B1) - (B2 - B3);   // sign parity of mask 0x7

    float P0 = red63(ls0 * q7);
    float P1 = red63(ls1 * tot);
    float P2 = red63(ls2 * tot);
    float P3 = red63(ls3 * tot);
    float P4 = red63(ls4 * tot);
    float P5 = red63(ls5 * tot);   // serves S5 (sigma +) and S6 (sigma -)
    float P7 = red63(ls5 * q4);
    float P8 = red63(ls5 * q6);
    float P9 = red63(ls5 * q7);
    if (lane == 63){
      float vals[10] = {P0,P1,P2,P3,P4,P5,P5,P7,P8,P9};
      #pragma unroll
      for (int j = 0; j < 10; ++j)
        ((float*)&partv[half][j])[g] = vals[j];
    }
    __syncthreads();

    // ---- combine partials + activations + cell (every lane, every wave) ----
    float4 eL = partv[0][lane];
    float4 eH = partv[1][lane];
    float E0 = fmaf(sig, eH.x, eL.x);
    float E1 = fmaf(sig, eH.y, eL.y);
    float E2 = fmaf(sig, eH.z, eL.z);
    float E3 = fmaf(sig, eH.w, eL.w);
    float fv = 1.f / (1.f + __expf(-E0));
    float iv = 1.f / (1.f + __expf(-E1));
    float e2g = __expf(2.f * E2);
    float gv = (e2g - 1.f) / (e2g + 1.f);
    float ov = 1.f / (1.f + __expf(-E3));
    c = fmaf(fv, c, iv * gv);
    float e2c = __expf(2.f * c);
    h = ov * ((e2c - 1.f) / (e2c + 1.f));

    if (wv == 0 && lane < NH)
      out[((size_t)t * BATCH + b) * NH + lane] = h;
  }

  // hT, cT
  if (wv == 0 && lane < NH){
    const size_t ysN = (size_t)T_STEPS * BATCH * NH;
    out[ysN + (size_t)b * NH + lane]                      = h;
    out[ysN + (size_t)BATCH * NH + (size_t)b * NH + lane] = c;
  }
}

extern "C" void kernel_launch(void* const* d_in, const int* in_sizes, int n_in,
                              void* d_out, int out_size, void* d_ws, size_t ws_size,
                              hipStream_t stream)
{
  qlstm_kernel<<<BATCH, 512, 0, stream>>>(
      (const float*)d_in[0], (const float*)d_in[1],
      (const float*)d_in[2], (const float*)d_in[3],
      (const float*)d_in[4], (const float*)d_in[5],
      (const float*)d_in[6], (const float*)d_in[7],
      (const float*)d_in[8], (const float*)d_in[9],
      (float*)d_out);
}

// Round 3
// 916.811 us; speedup vs baseline: 1.3502x; 1.0716x over previous
//
#include <hip/hip_runtime.h>
#include <math.h>

#define T_STEPS 256
#define BATCH   256
#define DDIM    128
#define NH      10

typedef float v2f __attribute__((ext_vector_type(2)));

__device__ __forceinline__ v2f sp(float x){ v2f r; r.x = x; r.y = x; return r; }
#define PKFMA(a,b,c) __builtin_elementwise_fma((a),(b),(c))

// ---------- DPP helpers (VALU pipe) ----------
template<int CTRL, int RMASK, int BMASK>
__device__ __forceinline__ float dppz(float x){
  return __int_as_float(__builtin_amdgcn_update_dpp(
      0, __float_as_int(x), CTRL, RMASK, BMASK, true));
}
template<int CTRL>
__device__ __forceinline__ float qperm(float x){
  int xi = __float_as_int(x);
  return __int_as_float(__builtin_amdgcn_update_dpp(xi, xi, CTRL, 0xF, 0xF, false));
}
// Canonical wave64 ladder (proven R4+): lane 63 ends with the full sum.
__device__ __forceinline__ float red63(float v){
  v += dppz<0x111, 0xF, 0xF>(v);
  v += dppz<0x112, 0xF, 0xF>(v);
  v += dppz<0x114, 0xF, 0xE>(v);
  v += dppz<0x118, 0xF, 0xC>(v);
  v += dppz<0x142, 0xA, 0xF>(v);
  v += dppz<0x143, 0xC, 0xF>(v);
  return v;
}
__device__ __forceinline__ float wave_sum_b(float v){
  return __int_as_float(__builtin_amdgcn_readlane(__float_as_int(red63(v)), 63));
}
__device__ __forceinline__ float qp2(float x){ return qperm<0x4E>(x); }  // quad xor2
__device__ __forceinline__ float qp1(float x){ return qperm<0xB1>(x); }  // quad xor1

// ---------- signed ladder stages ----------
// lad_add: plus-stage (same as red63's). lad_sub: minus-stage — at every
// block-complete lane on the lane-63 accumulation path the incoming value is
// the bit=0 block and self is the bit=1 block, so dpp(v)-v encodes (-1)^bit.
// Composing add/sub stages per bit yields sum_l (-1)^popc(l&M) v_l at lane 63
// (replaces the ls* pre-multiply + plain red63).
template<int CTRL, int RMASK, int BMASK>
__device__ __forceinline__ float lad_add(float v){ return v + dppz<CTRL,RMASK,BMASK>(v); }
template<int CTRL, int RMASK, int BMASK>
__device__ __forceinline__ float lad_sub(float v){ return dppz<CTRL,RMASK,BMASK>(v) - v; }

#define LAD0_A(v) lad_add<0x111,0xF,0xF>(v)
#define LAD0_S(v) lad_sub<0x111,0xF,0xF>(v)
#define LAD1_A(v) lad_add<0x112,0xF,0xF>(v)
#define LAD1_S(v) lad_sub<0x112,0xF,0xF>(v)
#define LAD2_A(v) lad_add<0x114,0xF,0xE>(v)
#define LAD2_S(v) lad_sub<0x114,0xF,0xE>(v)
#define LAD3_A(v) lad_add<0x118,0xF,0xC>(v)
#define LAD3_S(v) lad_sub<0x118,0xF,0xC>(v)
#define LAD4_A(v) lad_add<0x142,0xA,0xF>(v)
#define LAD4_S(v) lad_sub<0x142,0xA,0xF>(v)
#define LAD5_A(v) lad_add<0x143,0xC,0xF>(v)
#define LAD5_S(v) lad_sub<0x143,0xC,0xF>(v)

// ---------- ds-pipe xor fetchers (offload from the saturated VALU) ----------
__device__ __forceinline__ float dsx32(float x){ return __shfl_xor(x, 32, 64); }
__device__ __forceinline__ float dsx16(float x){
  return __int_as_float(__builtin_amdgcn_ds_swizzle(__float_as_int(x), 0x401F));
}
__device__ __forceinline__ float dsx8(float x){
  return __int_as_float(__builtin_amdgcn_ds_swizzle(__float_as_int(x), 0x201F));
}
__device__ __forceinline__ float dsx4(float x){
  return __int_as_float(__builtin_amdgcn_ds_swizzle(__float_as_int(x), 0x101F));
}

#define NK 4   // 4 packed pairs = 8 complex amps per lane (half statevector)

// RX on a lane-bit wire, packed: 2 fetches + 2 pk ops per pair.
#define RX_LANE_PK(FETCH, cv, sv)                                              \
  { const v2f cc_ = sp(cv), ss_ = sp(sv);                                      \
    _Pragma("unroll")                                                          \
    for (int k = 0; k < NK; ++k){                                              \
      v2f oa, ob;                                                              \
      oa.x = FETCH(RE[k].x); oa.y = FETCH(RE[k].y);                            \
      ob.x = FETCH(IM[k].x); ob.y = FETCH(IM[k].y);                            \
      RE[k] = PKFMA(cc_, RE[k], ss_ * ob);                                     \
      IM[k] = PKFMA(cc_, IM[k], -(ss_ * oa));                                  \
    } }

// RX on reg bit R2 (XB=2) / R1 (XB=1): partner pair is k^XB, no component swap.
template<int XB>
__device__ __forceinline__ void rx_reg_pk(float c, float s, v2f* RE, v2f* IM){
  const v2f cc = sp(c), ss = sp(s);
  v2f oR[NK], oI[NK];
  #pragma unroll
  for (int k = 0; k < NK; ++k){ oR[k] = RE[k]; oI[k] = IM[k]; }
  #pragma unroll
  for (int k = 0; k < NK; ++k){
    RE[k] = PKFMA(cc, oR[k],  ss * oI[k ^ XB]);
    IM[k] = PKFMA(cc, oI[k], -(ss * oR[k ^ XB]));
  }
}
// RX on reg bit R0: partner is the swapped component of the same pair.
__device__ __forceinline__ void rx_reg9_pk(float c, float s, v2f* RE, v2f* IM){
  const v2f cc = sp(c), ss = sp(s);
  #pragma unroll
  for (int k = 0; k < NK; ++k){
    v2f oa = __builtin_shufflevector(RE[k], RE[k], 1, 0);
    v2f ob = __builtin_shufflevector(IM[k], IM[k], 1, 0);
    RE[k] = PKFMA(cc, RE[k],  ss * ob);
    IM[k] = PKFMA(cc, IM[k], -(ss * oa));
  }
}

// ================= R8 layout (verified algebra, unchanged) =================
// Wave pair per gate: 512 amps/wave = 64 lanes x 8 regs (4 v2f pairs).
// Wires 0..5 -> lane bits 5..0, wire 6 -> wave bit (LDS exchange),
// wires 7,8,9 -> reg bits 2,1,0 (R0 = packed component).
__global__ void __launch_bounds__(512)
__attribute__((amdgpu_waves_per_eu(2)))
qlstm_kernel(const float* __restrict__ inp, const float* __restrict__ rxp,
             const float* __restrict__ Wf, const float* __restrict__ bf,
             const float* __restrict__ Wi, const float* __restrict__ bi,
             const float* __restrict__ Wg, const float* __restrict__ bg,
             const float* __restrict__ Wo, const float* __restrict__ bo,
             float* __restrict__ out)
{
  const int b    = blockIdx.x;
  const int tid  = threadIdx.x;
  const int wv   = tid >> 6;        // 0..7
  const int g    = wv >> 1;         // gate 0..3 (f,i,g,o)
  const int half = wv & 1;          // statevector half (wire-6 / wave bit)
  const int lane = tid & 63;

  // wire-6 exchange buffer: [gate][half][chunk][lane]
  __shared__ float4 Sx[4][2][4][64];
  // measurement partials, transposed: partv[half][j].{x,y,z,w} = gate f,i,g,o
  __shared__ float4 partv[2][64];
  // per-gate angle exchange: csn[gate][producer-half][k] = (cos, sin)
  // producer-half 0 publishes wires 0..4, half 1 wires 5..9.
  __shared__ float2 csn[4][2][5];
  ((float*)partv)[tid] = 0.f;       // 2*64*4 = 512 = blockDim

  const float* Wp = (g == 0) ? Wf : (g == 1) ? Wi : (g == 2) ? Wg : Wo;
  const float* bp = (g == 0) ? bf : (g == 1) ? bi : (g == 2) ? bg : bo;

  // Pre-scale weights by 0.5 (half-angle) * 1/(2pi) (v_sin/v_cos take
  // revolutions) so the per-step angle needs zero extra multiplies.
  const float WSC = 0.07957747154594767f;   // 1/(4*pi)
  v2f WA[5], WB[5], WC[5];
  float bT[NH];
  #pragma unroll
  for (int j = 0; j < 5; ++j){
    const int w0 = 2*j, w1 = 2*j + 1;
    WA[j].x = WSC * Wp[w0*138 + lane];        WA[j].y = WSC * Wp[w1*138 + lane];
    WB[j].x = WSC * Wp[w0*138 + 64 + lane];   WB[j].y = WSC * Wp[w1*138 + 64 + lane];
    WC[j].x = (lane < NH) ? WSC * Wp[w0*138 + 128 + lane] : 0.f;
    WC[j].y = (lane < NH) ? WSC * Wp[w1*138 + 128 + lane] : 0.f;
  }
  #pragma unroll
  for (int w = 0; w < NH; ++w) bT[w] = WSC * (bp[w] + rxp[w]);

  float pc[NH], ps[NH];
  #pragma unroll
  for (int w = 0; w < NH; ++w){
    float th = 0.5f * rxp[w];
    pc[w] = cosf(th);
    ps[w] = sinf(th);
  }

  // ---- hoisted lane/wave constants ----
  const int l5 = (lane>>5)&1, l4 = (lane>>4)&1, l3 = (lane>>3)&1;
  const int l2 = (lane>>2)&1, l1 = (lane>>1)&1, l0 = lane&1;
  const int pb2 = l4^l3, pb3 = l3^l2, pb4 = l2^l1, pb5 = l1^l0;
  const int a0 = l5, a1 = l5^l4;
  const int a6w = l0 ^ half;                       // beta6
  const int n_base = pb2 + pb3 + pb4 + pb5 + a6w;

  // phase constants (-i)^k per reg (step-invariant), packed over R0
  v2f CRE[NK], CIM[NK];
  #pragma unroll
  for (int r = 0; r < 2*NK; ++r){
    const int R0 = r&1, R1 = (r>>1)&1, R2 = (r>>2)&1;
    int k = (n_base + (a0^R0) + (a1^R0) + (half^R2) + (R2^R1) + (R1^R0)) & 3;
    float cr = (k==0) ? 1.f : (k==2) ? -1.f : 0.f;
    float ci = (k==1) ? -1.f : (k==3) ? 1.f : 0.f;
    if (R0){ CRE[r>>1].y = cr; CIM[r>>1].y = ci; }
    else   { CRE[r>>1].x = cr; CIM[r>>1].x = ci; }
  }

  // wave-sign at combine: sigma = -1 for hidden units {0, 6..9}
  const float sig = (lane == 0 || lane >= 6) ? -1.f : 1.f;

  float h = 0.f, c = 0.f;   // lane j holds h_j, c_j redundantly in every wave

  const float* x0 = inp + (size_t)b * DDIM;
  float xa = x0[lane];
  float xb = x0[64 + lane];

  __syncthreads();

  #pragma unroll 1
  for (int t = 0; t < T_STEPS; ++t){
    float xaC = xa, xbC = xb;
    if (t + 1 < T_STEPS){
      const float* nx = inp + ((size_t)(t+1) * BATCH + b) * DDIM;
      xa = nx[lane];
      xb = nx[64 + lane];
    }

    // ---- gate pre-activation angles, SPLIT across the pair halves ----
    // (angles in revolutions; scale folded into W). Each half computes 5
    // wires, publishes (cos,sin) via LDS, then reads the partner's 5.
    float cs[NH], sn[NH];
    {
      const v2f xav = sp(xaC), xbv = sp(xbC), hv = sp(h);
      if (half == 0){
        v2f p0 = PKFMA(xav, WA[0], PKFMA(xbv, WB[0], hv * WC[0]));
        v2f p1 = PKFMA(xav, WA[1], PKFMA(xbv, WB[1], hv * WC[1]));
        v2f p2 = PKFMA(xav, WA[2], PKFMA(xbv, WB[2], hv * WC[2]));
        float t0 = bT[0] + wave_sum_b(p0.x);
        float t1 = bT[1] + wave_sum_b(p0.y);
        float t2 = bT[2] + wave_sum_b(p1.x);
        float t3 = bT[3] + wave_sum_b(p1.y);
        float t4 = bT[4] + wave_sum_b(p2.x);
        cs[0] = __builtin_amdgcn_cosf(t0); sn[0] = __builtin_amdgcn_sinf(t0);
        cs[1] = __builtin_amdgcn_cosf(t1); sn[1] = __builtin_amdgcn_sinf(t1);
        cs[2] = __builtin_amdgcn_cosf(t2); sn[2] = __builtin_amdgcn_sinf(t2);
        cs[3] = __builtin_amdgcn_cosf(t3); sn[3] = __builtin_amdgcn_sinf(t3);
        cs[4] = __builtin_amdgcn_cosf(t4); sn[4] = __builtin_amdgcn_sinf(t4);
        if (lane == 0){
          csn[g][0][0] = make_float2(cs[0], sn[0]);
          csn[g][0][1] = make_float2(cs[1], sn[1]);
          csn[g][0][2] = make_float2(cs[2], sn[2]);
          csn[g][0][3] = make_float2(cs[3], sn[3]);
          csn[g][0][4] = make_float2(cs[4], sn[4]);
        }
      } else {
        v2f p2 = PKFMA(xav, WA[2], PKFMA(xbv, WB[2], hv * WC[2]));
        v2f p3 = PKFMA(xav, WA[3], PKFMA(xbv, WB[3], hv * WC[3]));
        v2f p4 = PKFMA(xav, WA[4], PKFMA(xbv, WB[4], hv * WC[4]));
        float t5 = bT[5] + wave_sum_b(p2.y);
        float t6 = bT[6] + wave_sum_b(p3.x);
        float t7 = bT[7] + wave_sum_b(p3.y);
        float t8 = bT[8] + wave_sum_b(p4.x);
        float t9 = bT[9] + wave_sum_b(p4.y);
        cs[5] = __builtin_amdgcn_cosf(t5); sn[5] = __builtin_amdgcn_sinf(t5);
        cs[6] = __builtin_amdgcn_cosf(t6); sn[6] = __builtin_amdgcn_sinf(t6);
        cs[7] = __builtin_amdgcn_cosf(t7); sn[7] = __builtin_amdgcn_sinf(t7);
        cs[8] = __builtin_amdgcn_cosf(t8); sn[8] = __builtin_amdgcn_sinf(t8);
        cs[9] = __builtin_amdgcn_cosf(t9); sn[9] = __builtin_amdgcn_sinf(t9);
        if (lane == 0){
          csn[g][1][0] = make_float2(cs[5], sn[5]);
          csn[g][1][1] = make_float2(cs[6], sn[6]);
          csn[g][1][2] = make_float2(cs[7], sn[7]);
          csn[g][1][3] = make_float2(cs[8], sn[8]);
          csn[g][1][4] = make_float2(cs[9], sn[9]);
        }
      }
    }
    __syncthreads();   // barrier 3: angle publish
    if (half == 0){
      float2 o0 = csn[g][1][0]; cs[5] = o0.x; sn[5] = o0.y;
      float2 o1 = csn[g][1][1]; cs[6] = o1.x; sn[6] = o1.y;
      float2 o2 = csn[g][1][2]; cs[7] = o2.x; sn[7] = o2.y;
      float2 o3 = csn[g][1][3]; cs[8] = o3.x; sn[8] = o3.y;
      float2 o4 = csn[g][1][4]; cs[9] = o4.x; sn[9] = o4.y;
    } else {
      float2 o0 = csn[g][0][0]; cs[0] = o0.x; sn[0] = o0.y;
      float2 o1 = csn[g][0][1]; cs[1] = o1.x; sn[1] = o1.y;
      float2 o2 = csn[g][0][2]; cs[2] = o2.x; sn[2] = o2.y;
      float2 o3 = csn[g][0][3]; cs[3] = o3.x; sn[3] = o3.y;
      float2 o4 = csn[g][0][4]; cs[4] = o4.x; sn[4] = o4.y;
    }

    // ---- build half-statevector: u[j] = prod-state(x+p) at K j ----
    float f2 = pb2 ? sn[2] : cs[2];
    float f3 = pb3 ? sn[3] : cs[3];
    float f4 = pb4 ? sn[4] : cs[4];
    float f5 = pb5 ? sn[5] : cs[5];
    float m2345 = ((f2*f3)*(f4*f5)) * (a6w ? sn[6] : cs[6]);  // wire-6 folded

    float q0 = (a0 ? sn[0] : cs[0]) * (a1 ? sn[1] : cs[1]);
    float q1 = (a0 ? cs[0] : sn[0]) * (a1 ? cs[1] : sn[1]);
    v2f ZZ; ZZ.x = m2345 * q0; ZZ.y = m2345 * q1;

    float u7  = half ? sn[7] : cs[7];
    float u7b = half ? cs[7] : sn[7];
    float t78[4];
    t78[0] = u7  * cs[8];   // k=0: R2=0,R1=0
    t78[1] = u7  * sn[8];   // k=1: R2=0,R1=1
    t78[2] = u7b * sn[8];   // k=2: R2=1,R1=0
    t78[3] = u7b * cs[8];   // k=3: R2=1,R1=1

    v2f s9a; s9a.x = cs[9]; s9a.y = sn[9];   // k even: b9 = R1^R0 = (0,1)
    v2f s9b; s9b.x = sn[9]; s9b.y = cs[9];   // k odd:  b9 = (1,0)

    v2f RE[NK], IM[NK];
    #pragma unroll
    for (int k = 0; k < NK; ++k){
      v2f M = (sp(t78[k]) * ((k & 1) ? s9b : s9a)) * ZZ;
      RE[k] = M * CRE[k];
      IM[k] = M * CIM[k];
    }

    // ---- RX(p): lane wires 0..5 (ds-pipe fetch for 0..3), reg wires 7..9 ----
    RX_LANE_PK(dsx32, pc[0], ps[0])
    RX_LANE_PK(dsx16, pc[1], ps[1])
    RX_LANE_PK(dsx8,  pc[2], ps[2])
    RX_LANE_PK(dsx4,  pc[3], ps[3])
    RX_LANE_PK(qp2,   pc[4], ps[4])
    RX_LANE_PK(qp1,   pc[5], ps[5])
    rx_reg_pk<2>(pc[7], ps[7], RE, IM);
    rx_reg_pk<1>(pc[8], ps[8], RE, IM);
    rx_reg9_pk  (pc[9], ps[9], RE, IM);

    // wire 6 (wave bit): exchange full half-state with partner wave via LDS
    Sx[g][half][0][lane] = make_float4(RE[0].x, RE[0].y, RE[1].x, RE[1].y);
    Sx[g][half][1][lane] = make_float4(RE[2].x, RE[2].y, RE[3].x, RE[3].y);
    Sx[g][half][2][lane] = make_float4(IM[0].x, IM[0].y, IM[1].x, IM[1].y);
    Sx[g][half][3][lane] = make_float4(IM[2].x, IM[2].y, IM[3].x, IM[3].y);
    __syncthreads();   // barrier 1: wire-6 exchange
    {
      float4 pr0 = Sx[g][half^1][0][lane];
      float4 pr1 = Sx[g][half^1][1][lane];
      float4 pi0 = Sx[g][half^1][2][lane];
      float4 pi1 = Sx[g][half^1][3][lane];
      v2f PR[NK], PI[NK];
      PR[0].x = pr0.x; PR[0].y = pr0.y; PR[1].x = pr0.z; PR[1].y = pr0.w;
      PR[2].x = pr1.x; PR[2].y = pr1.y; PR[3].x = pr1.z; PR[3].y = pr1.w;
      PI[0].x = pi0.x; PI[0].y = pi0.y; PI[1].x = pi0.z; PI[1].y = pi0.w;
      PI[2].x = pi1.x; PI[2].y = pi1.y; PI[3].x = pi1.z; PI[3].y = pi1.w;
      const v2f c6 = sp(pc[6]), s6 = sp(ps[6]);
      #pragma unroll
      for (int k = 0; k < NK; ++k){
        RE[k] = PKFMA(c6, RE[k],  s6 * PI[k]);
        IM[k] = PKFMA(c6, IM[k], -(s6 * PR[k]));
      }
    }

    // ---- PauliZ partials: packed |psi|^2 + shared pair-tree ----
    v2f Pk[NK];
    #pragma unroll
    for (int k = 0; k < NK; ++k) Pk[k] = PKFMA(RE[k], RE[k], IM[k] * IM[k]);
    float A0 = Pk[0].x + Pk[0].y, A1 = Pk[1].x + Pk[1].y;
    float A2 = Pk[2].x + Pk[2].y, A3 = Pk[3].x + Pk[3].y;
    float B0 = Pk[0].x - Pk[0].y, B1 = Pk[1].x - Pk[1].y;
    float B2 = Pk[2].x - Pk[2].y, B3 = Pk[3].x - Pk[3].y;
    float su = A0 + A1, sv = A2 + A3;
    float tot = su + sv;                 // plain sum
    float q4  = su - sv;                 // sign on R2
    float q6  = (A0 - A1) - (A2 - A3);   // sign parity of R2^R1 mask 0x6
    float q7  = (B0 - B1) - (B2 - B3);   // sign parity of mask 0x7

    // ---- shared signed-ladder reductions (sign masks encoded as add/sub) ----
    // tot-family: P1..P5 with nested lane masks 0x30,0x38,0x3C,0x3E,0x3F
    float a0p = LAD0_A(tot);
    float a0m = LAD0_S(tot);
    float b1pp = LAD1_A(a0p);
    float b1pm = LAD1_S(a0p);
    float b1mm = LAD1_S(a0m);
    float c2ppp = LAD2_A(b1pp);
    float c2ppm = LAD2_S(b1pp);
    float c2pmm = LAD2_S(b1pm);
    float c2mmm = LAD2_S(b1mm);
    float d1 = LAD3_A(c2ppp);   // P1: ++++ then --
    float d2 = LAD3_S(c2ppp);   // P2: +++-
    float d3 = LAD3_S(c2ppm);   // P3: ++--
    float d4 = LAD3_S(c2pmm);   // P4: +---
    float d5 = LAD3_S(c2mmm);   // P5: ----
    float P1 = LAD5_S(LAD4_S(d1));
    float P2 = LAD5_S(LAD4_S(d2));
    float P3 = LAD5_S(LAD4_S(d3));
    float P4 = LAD5_S(LAD4_S(d4));
    float P5 = LAD5_S(LAD4_S(d5));   // serves S5 (sigma +) and S6 (sigma -)
    // q7: P9 = all-minus (mask 0x3F); P0 = minus bits0-4, plus bit5 (0x1F)
    float e = LAD0_S(q7);
    e = LAD1_S(e); e = LAD2_S(e); e = LAD3_S(e); e = LAD4_S(e);
    float P9 = LAD5_S(e);
    float P0 = LAD5_A(e);
    // q4, q6: all-minus (mask 0x3F)
    float f_ = LAD0_S(q4);
    f_ = LAD1_S(f_); f_ = LAD2_S(f_); f_ = LAD3_S(f_); f_ = LAD4_S(f_);
    float P7 = LAD5_S(f_);
    float g_ = LAD0_S(q6);
    g_ = LAD1_S(g_); g_ = LAD2_S(g_); g_ = LAD3_S(g_); g_ = LAD4_S(g_);
    float P8 = LAD5_S(g_);

    if (lane == 63){
      float vals[10] = {P0,P1,P2,P3,P4,P5,P5,P7,P8,P9};
      #pragma unroll
      for (int j = 0; j < 10; ++j)
        ((float*)&partv[half][j])[g] = vals[j];
    }
    __syncthreads();   // barrier 2: measurement partials

    // ---- combine partials + activations + cell (every lane, every wave) ----
    float4 eL = partv[0][lane];
    float4 eH = partv[1][lane];
    float E0 = fmaf(sig, eH.x, eL.x);
    float E1 = fmaf(sig, eH.y, eL.y);
    float E2 = fmaf(sig, eH.z, eL.z);
    float E3 = fmaf(sig, eH.w, eL.w);
    float fv = 1.f / (1.f + __expf(-E0));
    float iv = 1.f / (1.f + __expf(-E1));
    float e2g = __expf(2.f * E2);
    float gv = (e2g - 1.f) / (e2g + 1.f);
    float ov = 1.f / (1.f + __expf(-E3));
    c = fmaf(fv, c, iv * gv);
    float e2c = __expf(2.f * c);
    h = ov * ((e2c - 1.f) / (e2c + 1.f));

    if (wv == 0 && lane < NH)
      out[((size_t)t * BATCH + b) * NH + lane] = h;
  }

  // hT, cT
  if (wv == 0 && lane < NH){
    const size_t ysN = (size_t)T_STEPS * BATCH * NH;
    out[ysN + (size_t)b * NH + lane]                      = h;
    out[ysN + (size_t)BATCH * NH + (size_t)b * NH + lane] = c;
  }
}

extern "C" void kernel_launch(void* const* d_in, const int* in_sizes, int n_in,
                              void* d_out, int out_size, void* d_ws, size_t ws_size,
                              hipStream_t stream)
{
  qlstm_kernel<<<BATCH, 512, 0, stream>>>(
      (const float*)d_in[0], (const float*)d_in[1],
      (const float*)d_in[2], (const float*)d_in[3],
      (const float*)d_in[4], (const float*)d_in[5],
      (const float*)d_in[6], (const float*)d_in[7],
      (const float*)d_in[8], (const float*)d_in[9],
      (float*)d_out);
}